// Round 3
// baseline (543.295 us; speedup 1.0000x reference)
//
#include <hip/hip_runtime.h>
#include <hip/hip_bf16.h>
#include <math.h>

// B=32, L=2048, D_Q=D_V=1024, UNITS=512
#define NB 32
#define LL 2048
#define DV 1024
#define NU 512
#define NM (NB * LL)

typedef __attribute__((ext_vector_type(8))) short short8;
typedef __attribute__((ext_vector_type(4))) float f32x4;

#define GLL16(g, l)                                                            \
  __builtin_amdgcn_global_load_lds(                                            \
      (const __attribute__((address_space(1))) void*)(g),                      \
      (__attribute__((address_space(3))) void*)(l), 16, 0, 0)

__device__ __forceinline__ float fast_tanh(float x) {
  x = fminf(fmaxf(x, -15.f), 15.f);
  float e = __expf(2.f * x);
  return (e - 1.f) / (e + 1.f);
}

// ---------------------------------------------------------------------------
__global__ __launch_bounds__(256) void masksum_kernel(
    const float* __restrict__ mask, float* __restrict__ loglen) {
  int b = blockIdx.x, tid = threadIdx.x;
  int lane = tid & 63, wid = tid >> 6;
  float c = 0.f;
#pragma unroll
  for (int j = 0; j < 8; j++)
    c += (mask[(size_t)b * LL + j * 256 + tid] == 0.f) ? 1.f : 0.f;
#pragma unroll
  for (int o = 32; o >= 1; o >>= 1) c += __shfl_xor(c, o, 64);
  __shared__ float red[4];
  if (lane == 0) red[wid] = c;
  __syncthreads();
  if (tid == 0) loglen[b] = logf(1.f + red[0] + red[1] + red[2] + red[3]);
}

// ---------------------------------------------------------------------------
// Pack Wv -> bf16, layout [ntile(2)][kt(32)][chunk(1024) of 16B], with the
// XOR chunk swizzle baked in: chunk j = n*4+c holds k-quad q = c ^ ((n>>1)&3).
// Register-transpose version: thread loads 8 coalesced float4 rows
// (4 consecutive u for k0..k0+7) and emits 4 packed 16B chunks.
__global__ __launch_bounds__(256) void wvpack_kernel(
    const float* __restrict__ Wv, __hip_bfloat16* __restrict__ wvpk) {
  int t = blockIdx.x * 256 + threadIdx.x;  // 16384 threads
  int u4 = t & 127;                        // u-group of 4
  int kg = t >> 7;                         // k-group of 8 (0..127)
  int k0 = kg * 8;
  int kt = kg >> 2;
  int q = kg & 3;
  float4 f[8];
#pragma unroll
  for (int j = 0; j < 8; j++)
    f[j] = *(const float4*)(Wv + (size_t)(k0 + j) * NU + u4 * 4);
#pragma unroll
  for (int e = 0; e < 4; e++) {
    int u = u4 * 4 + e;
    int nt = u >> 8, n = u & 255;
    int c = q ^ ((n >> 1) & 3);
    int idx = nt * 32768 + kt * 1024 + n * 4 + c;
    const float* fe = (const float*)&f[0] + e;  // stride 4 floats per row
    union {
      __hip_bfloat162 h2[4];
      int4 v;
    } pk;
#pragma unroll
    for (int m = 0; m < 4; m++)
      pk.h2[m] = __float22bfloat162_rn(make_float2(fe[(2 * m) * 4], fe[(2 * m + 1) * 4]));
    ((int4*)wvpk)[idx] = pk.v;
  }
}

// ---------------------------------------------------------------------------
// h[b,u] = q@Wh + biases + log(1+ts)*Wp0 + loglen*Wp2.
// Full-K per thread: no atomics, no memset. Grid (8 uslab, 4 bq), 256 thr =
// 64 u x 4 bsub; each thread accumulates 2 b's over all 1024 k.
__global__ __launch_bounds__(256) void h_kernel(
    const float* __restrict__ q, const float* __restrict__ Wh,
    const float* __restrict__ bh, const float* __restrict__ bv,
    const float* __restrict__ bp, const float* __restrict__ bm,
    const float* __restrict__ Wp, const int* __restrict__ ts,
    const float* __restrict__ loglen, float* __restrict__ h) {
  int u0 = blockIdx.x * 64;
  int bq = blockIdx.y;
  int tid = threadIdx.x;
  int u = tid & 63, bsub = tid >> 6;
  int b0 = bq * 8 + bsub * 2, b1 = b0 + 1;

  __shared__ float qsL[8][1024];  // 32 KB: q rows for this bq's 8 b's
#pragma unroll
  for (int j = 0; j < 8; j++) {
    int f = j * 256 + tid;  // float4 index in [0,2048)
    int bl = f >> 8, k4 = f & 255;
    *(float4*)&qsL[bl][k4 * 4] =
        *(const float4*)(q + (size_t)(bq * 8 + bl) * 1024 + k4 * 4);
  }
  __syncthreads();

  float a0e = 0.f, a0o = 0.f, a1e = 0.f, a1o = 0.f;
#pragma unroll 16
  for (int k = 0; k < 1024; k += 2) {
    float w0 = Wh[(size_t)k * NU + u0 + u];
    float w1 = Wh[(size_t)(k + 1) * NU + u0 + u];
    a0e += w0 * qsL[bsub * 2][k];
    a1e += w0 * qsL[bsub * 2 + 1][k];
    a0o += w1 * qsL[bsub * 2][k + 1];
    a1o += w1 * qsL[bsub * 2 + 1][k + 1];
  }
  float acc0 = a0e + a0o, acc1 = a1e + a1o;

  int uu = u0 + u;
  float lt = logf(1.0f + (float)ts[0]);
  float bias = bh[uu] + bv[uu] + bp[uu] + bm[uu] + lt * Wp[uu];
  float wp2 = Wp[2 * NU + uu];
  h[b0 * NU + uu] = acc0 + bias + loglen[b0] * wp2;
  h[b1 * NU + uu] = acc1 + bias + loglen[b1] * wp2;
}

// ---------------------------------------------------------------------------
// Score: S = values@Wv (bf16 MFMA), epilogue tanh(S+E)*vw reduced over u.
// (unchanged from R1)
__global__ __launch_bounds__(256, 2) void score_kernel(
    const float* __restrict__ values, const __hip_bfloat16* __restrict__ wvpk,
    const float* __restrict__ h, const float* __restrict__ Wp,
    const float* __restrict__ Wm, const float* __restrict__ vw,
    const float* __restrict__ prev, float* __restrict__ partial) {
  int lin = blockIdx.x;
  int group = lin >> 4, sub = lin & 15;
  int ntile = sub >> 3;                 // 0..1
  int mtile = group * 8 + (sub & 7);    // 0..511
  int tid = threadIdx.x;
  int lane = tid & 63, wid = tid >> 6;
  int wr = wid >> 1, wc = wid & 1;
  int col = lane & 15, quad = lane >> 4;
  int b = mtile >> 4;
  int l0 = (mtile & 15) << 7;
  int rowbase = mtile << 7;

  __shared__ __align__(16) char AsB[2][8192];   // 128 rows x 64B, xor-swizzled
  __shared__ __align__(16) char BsB[2][16384];  // 256 cols x 64B, xor-swizzled
  __shared__ float hL[256], wp1L[256], vwL[256], wmL[5][256];
  __shared__ float loglS[128], prevs[132], scoreAcc[128];

  {
    int u = ntile * 256 + tid;
    hL[tid] = h[b * NU + u];
    wp1L[tid] = Wp[NU + u];
    vwL[tid] = vw[u];
#pragma unroll
    for (int j = 0; j < 5; j++) wmL[j][tid] = Wm[j * NU + u];
  }
  if (tid < 128) {
    loglS[tid] = __logf(2.0f + (float)(l0 + tid));
    scoreAcc[tid] = 0.f;
  }
  if (tid < 132) {
    int li = l0 - 2 + tid;
    prevs[tid] = (li >= 0 && li < LL) ? prev[(size_t)b * LL + li] : 0.f;
  }

  f32x4 acc[4][8];
  f32x4 zero4 = {0.f, 0.f, 0.f, 0.f};
#pragma unroll
  for (int i = 0; i < 4; i++)
#pragma unroll
    for (int j = 0; j < 8; j++) acc[i][j] = zero4;

  int row = tid >> 1, h0 = tid & 1;
  const float* abase = values + (size_t)(rowbase + row) * DV + h0 * 16;
  int s_sw = (row >> 1) & 3;
  int aoff0 = row * 64 + (((h0 * 2) ^ s_sw) * 16);
  int aoff1 = row * 64 + (((h0 * 2 + 1) ^ s_sw) * 16);
  const char* bbase = (const char*)wvpk + (size_t)ntile * 32 * 16384;
  int boff = tid * 16;

  float4 preA[2][4];

  {
#pragma unroll
    for (int d = 0; d < 2; d++) {
      const float4* p = (const float4*)(abase + d * 32);
#pragma unroll
      for (int j = 0; j < 4; j++) preA[d][j] = p[j];
    }
    GLL16(bbase + boff, BsB[0] + boff);
    GLL16(bbase + boff + 4096, BsB[0] + boff + 4096);
    GLL16(bbase + boff + 8192, BsB[0] + boff + 8192);
    GLL16(bbase + boff + 12288, BsB[0] + boff + 12288);
    float4 f0 = preA[0][0], f1 = preA[0][1];
    float4 f2 = preA[0][2], f3 = preA[0][3];
    union {
      __hip_bfloat162 h2[8];
      int4 qq[2];
    } pk;
    pk.h2[0] = __float22bfloat162_rn(make_float2(f0.x, f0.y));
    pk.h2[1] = __float22bfloat162_rn(make_float2(f0.z, f0.w));
    pk.h2[2] = __float22bfloat162_rn(make_float2(f1.x, f1.y));
    pk.h2[3] = __float22bfloat162_rn(make_float2(f1.z, f1.w));
    pk.h2[4] = __float22bfloat162_rn(make_float2(f2.x, f2.y));
    pk.h2[5] = __float22bfloat162_rn(make_float2(f2.z, f2.w));
    pk.h2[6] = __float22bfloat162_rn(make_float2(f3.x, f3.y));
    pk.h2[7] = __float22bfloat162_rn(make_float2(f3.z, f3.w));
    *(int4*)(AsB[0] + aoff0) = pk.qq[0];
    *(int4*)(AsB[0] + aoff1) = pk.qq[1];
    const float4* nx = (const float4*)(abase + 2 * 32);
    preA[0][0] = nx[0];
    preA[0][1] = nx[1];
    preA[0][2] = nx[2];
    preA[0][3] = nx[3];
    __syncthreads();
  }

#define KSTEP(KT, CBUF, OSLOT, DO_STAGE, DO_RELOAD)                            \
  {                                                                            \
    if (DO_STAGE) {                                                            \
      const char* bsrc = bbase + (size_t)((KT) + 1) * 16384;                   \
      GLL16(bsrc + boff, BsB[(CBUF) ^ 1] + boff);                              \
      GLL16(bsrc + boff + 4096, BsB[(CBUF) ^ 1] + boff + 4096);                \
      GLL16(bsrc + boff + 8192, BsB[(CBUF) ^ 1] + boff + 8192);                \
      GLL16(bsrc + boff + 12288, BsB[(CBUF) ^ 1] + boff + 12288);              \
      float4 f0 = preA[OSLOT][0], f1 = preA[OSLOT][1];                         \
      float4 f2 = preA[OSLOT][2], f3 = preA[OSLOT][3];                         \
      union {                                                                  \
        __hip_bfloat162 h2[8];                                                 \
        int4 qq[2];                                                            \
      } pk;                                                                    \
      pk.h2[0] = __float22bfloat162_rn(make_float2(f0.x, f0.y));               \
      pk.h2[1] = __float22bfloat162_rn(make_float2(f0.z, f0.w));               \
      pk.h2[2] = __float22bfloat162_rn(make_float2(f1.x, f1.y));               \
      pk.h2[3] = __float22bfloat162_rn(make_float2(f1.z, f1.w));               \
      pk.h2[4] = __float22bfloat162_rn(make_float2(f2.x, f2.y));               \
      pk.h2[5] = __float22bfloat162_rn(make_float2(f2.z, f2.w));               \
      pk.h2[6] = __float22bfloat162_rn(make_float2(f3.x, f3.y));               \
      pk.h2[7] = __float22bfloat162_rn(make_float2(f3.z, f3.w));               \
      *(int4*)(AsB[(CBUF) ^ 1] + aoff0) = pk.qq[0];                            \
      *(int4*)(AsB[(CBUF) ^ 1] + aoff1) = pk.qq[1];                            \
      if (DO_RELOAD) {                                                         \
        const float4* nx = (const float4*)(abase + ((KT) + 3) * 32);           \
        preA[OSLOT][0] = nx[0];                                                \
        preA[OSLOT][1] = nx[1];                                                \
        preA[OSLOT][2] = nx[2];                                                \
        preA[OSLOT][3] = nx[3];                                                \
      }                                                                        \
    }                                                                          \
    short8 aF[4];                                                              \
    _Pragma("unroll") for (int t = 0; t < 4; t++) {                            \
      int m = wr * 64 + t * 16 + col;                                          \
      aF[t] = *(const short8*)(AsB[CBUF] + m * 64 +                            \
                               ((quad ^ ((m >> 1) & 3)) * 16));                \
    }                                                                          \
    _Pragma("unroll") for (int tc = 0; tc < 8; tc++) {                         \
      int n = wc * 128 + tc * 16 + col;                                        \
      short8 bF =                                                              \
          *(const short8*)(BsB[CBUF] + n * 64 + ((quad ^ ((n >> 1) & 3)) * 16)); \
      _Pragma("unroll") for (int tr = 0; tr < 4; tr++) acc[tr][tc] =           \
          __builtin_amdgcn_mfma_f32_16x16x32_bf16(aF[tr], bF, acc[tr][tc], 0,  \
                                                  0, 0);                       \
    }                                                                          \
    __syncthreads();                                                           \
  }

  for (int kto = 0; kto < 14; kto++) {
    KSTEP(2 * kto, 0, 1, 1, 1);
    KSTEP(2 * kto + 1, 1, 0, 1, 1);
  }
  KSTEP(28, 0, 1, 1, 1);
  KSTEP(29, 1, 0, 1, 0);
  KSTEP(30, 0, 1, 1, 0);
  KSTEP(31, 1, 0, 0, 0);
#undef KSTEP

  int rb = wr * 64;
#pragma unroll
  for (int tr = 0; tr < 4; tr++) {
    float ps[4] = {0.f, 0.f, 0.f, 0.f};
#pragma unroll
    for (int tc = 0; tc < 8; tc++) {
      int uc = wc * 128 + tc * 16 + col;
      float hh = hL[uc], wp1 = wp1L[uc], vv = vwL[uc];
      float m0 = wmL[0][uc], m1 = wmL[1][uc], m2 = wmL[2][uc],
            m3 = wmL[3][uc], m4 = wmL[4][uc];
      int r0 = rb + tr * 16 + quad * 4;
#pragma unroll
      for (int i = 0; i < 4; i++) {
        int r = r0 + i;
        float e = hh + loglS[r] * wp1 + prevs[r] * m0 + prevs[r + 1] * m1 +
                  prevs[r + 2] * m2 + prevs[r + 3] * m3 + prevs[r + 4] * m4;
        float sv = acc[tr][tc][i] + e;
        ps[i] += fast_tanh(sv) * vv;
      }
    }
#pragma unroll
    for (int i = 0; i < 4; i++) {
      float v = ps[i];
      v += __shfl_xor(v, 1, 64);
      v += __shfl_xor(v, 2, 64);
      v += __shfl_xor(v, 4, 64);
      v += __shfl_xor(v, 8, 64);
      if (col == 0) atomicAdd(&scoreAcc[rb + tr * 16 + quad * 4 + i], v);
    }
  }
  __syncthreads();
  if (tid < 128)
    partial[(size_t)ntile * NM + rowbase + tid] = scoreAcc[tid];
}

// ---------------------------------------------------------------------------
__global__ __launch_bounds__(256) void softmax_kernel(
    const float* __restrict__ partial, const float* __restrict__ mask,
    float* __restrict__ aw) {
  int b = blockIdx.x, tid = threadIdx.x;
  int lane = tid & 63, wid = tid >> 6;
  __shared__ float redmax[4], redsum[4];
  float sc[8];
  float mx = -3.0e38f;
#pragma unroll
  for (int j = 0; j < 8; j++) {
    size_t base = (size_t)b * LL + j * 256 + tid;
    float s = partial[base] + partial[(size_t)NM + base];
    s += mask[base] * -1.0e9f;
    sc[j] = s;
    mx = fmaxf(mx, s);
  }
#pragma unroll
  for (int o = 32; o >= 1; o >>= 1) mx = fmaxf(mx, __shfl_xor(mx, o, 64));
  if (lane == 0) redmax[wid] = mx;
  __syncthreads();
  mx = fmaxf(fmaxf(redmax[0], redmax[1]), fmaxf(redmax[2], redmax[3]));
  float sum = 0.f;
#pragma unroll
  for (int j = 0; j < 8; j++) {
    float e = __expf(sc[j] - mx);
    sc[j] = e;
    sum += e;
  }
#pragma unroll
  for (int o = 32; o >= 1; o >>= 1) sum += __shfl_xor(sum, o, 64);
  if (lane == 0) redsum[wid] = sum;
  __syncthreads();
  sum = redsum[0] + redsum[1] + redsum[2] + redsum[3];
  float inv = 1.0f / sum;
#pragma unroll
  for (int j = 0; j < 8; j++)
    aw[(size_t)b * LL + j * 256 + tid] = sc[j] * inv;
}

// ---------------------------------------------------------------------------
// ctx: grid 64 blocks (b, half), 1024 threads. Block owns 1024 contiguous
// rows; aw staged in LDS; in-block LDS reduction over 4 row-groups; ONE
// atomicAdd x4 per (b, v4-slot) per block -> 65k atomic-lane-ops total.
__global__ __launch_bounds__(1024) void ctx_kernel(
    const float* __restrict__ values, const float* __restrict__ aw,
    float* __restrict__ out) {
  int b = blockIdx.x >> 1, half = blockIdx.x & 1;
  int tid = threadIdx.x;
  int s = tid & 255, rg = tid >> 8;
  int l0 = half * 1024;

  __shared__ float awL[1024];
  __shared__ f32x4 red[4][256];

  awL[tid] = aw[(size_t)b * LL + l0 + tid];
  __syncthreads();

  const float4* vbase =
      (const float4*)(values + ((size_t)b * LL + l0 + rg * 256) * DV) + s;
  const float* awr = awL + rg * 256;
  float4 acc = make_float4(0.f, 0.f, 0.f, 0.f);
  for (int i0 = 0; i0 < 256; i0 += 8) {
    float4 v[8];
#pragma unroll
    for (int j = 0; j < 8; j++) v[j] = vbase[(size_t)(i0 + j) * 256];
#pragma unroll
    for (int j = 0; j < 8; j++) {
      float w = awr[i0 + j];
      acc.x += w * v[j].x;
      acc.y += w * v[j].y;
      acc.z += w * v[j].z;
      acc.w += w * v[j].w;
    }
  }
  f32x4 a4 = {acc.x, acc.y, acc.z, acc.w};
  red[rg][s] = a4;
  __syncthreads();
  if (tid < 256) {
    f32x4 r = red[0][s];
    f32x4 r1 = red[1][s], r2 = red[2][s], r3 = red[3][s];
    r += r1;
    r += r2;
    r += r3;
    float* o = out + (size_t)b * DV + s * 4;
    atomicAdd(o + 0, r[0]);
    atomicAdd(o + 1, r[1]);
    atomicAdd(o + 2, r[2]);
    atomicAdd(o + 3, r[3]);
  }
}

// ---------------------------------------------------------------------------
extern "C" void kernel_launch(void* const* d_in, const int* in_sizes, int n_in,
                              void* d_out, int out_size, void* d_ws,
                              size_t ws_size, hipStream_t stream) {
  const float* query = (const float*)d_in[0];
  const float* values = (const float*)d_in[1];
  const float* mask = (const float*)d_in[2];
  const float* prev = (const float*)d_in[3];
  const int* ts = (const int*)d_in[4];
  const float* Wh = (const float*)d_in[5];
  const float* bh = (const float*)d_in[6];
  const float* Wv = (const float*)d_in[7];
  const float* bv = (const float*)d_in[8];
  const float* Wp = (const float*)d_in[9];
  const float* bp = (const float*)d_in[10];
  const float* Wm = (const float*)d_in[11];
  const float* bm = (const float*)d_in[12];
  const float* vw = (const float*)d_in[13];
  // d_in[14] = vb: cancels under softmax.

  float* out = (float*)d_out;   // [0,32768) ctx, [32768,98304) aw
  float* ws = (float*)d_ws;
  float* loglen = ws;                    // 32 f
  float* h = ws + 1024;                  // 16384 f
  float* partial = ws + 32768;           // 2*65536 f
  __hip_bfloat16* wvpk =
      (__hip_bfloat16*)((char*)d_ws + (size_t)163840 * 4);  // 1 MB
  float* aw = out + 32768;

  hipMemsetAsync(d_out, 0, 32768 * sizeof(float), stream);  // ctx accumulator
  masksum_kernel<<<NB, 256, 0, stream>>>(mask, loglen);
  wvpack_kernel<<<64, 256, 0, stream>>>(Wv, wvpk);
  h_kernel<<<dim3(8, 4), 256, 0, stream>>>(query, Wh, bh, bv, bp, bm, Wp, ts,
                                           loglen, h);
  score_kernel<<<1024, 256, 0, stream>>>(values, wvpk, h, Wp, Wm, vw, prev,
                                         partial);
  softmax_kernel<<<NB, 256, 0, stream>>>(partial, mask, aw);
  ctx_kernel<<<64, 1024, 0, stream>>>(values, aw, out);
}

// Round 4
// 524.133 us; speedup vs baseline: 1.0366x; 1.0366x over previous
//
#include <hip/hip_runtime.h>
#include <hip/hip_bf16.h>
#include <math.h>

// B=32, L=2048, D_Q=D_V=1024, UNITS=512
#define NB 32
#define LL 2048
#define DV 1024
#define NU 512
#define NM (NB * LL)

typedef __attribute__((ext_vector_type(8))) short short8;
typedef __attribute__((ext_vector_type(4))) float f32x4;

#define GLL16(g, l)                                                            \
  __builtin_amdgcn_global_load_lds(                                            \
      (const __attribute__((address_space(1))) void*)(g),                      \
      (__attribute__((address_space(3))) void*)(l), 16, 0, 0)

__device__ __forceinline__ float fast_tanh(float x) {
  x = fminf(fmaxf(x, -15.f), 15.f);
  float e = __expf(2.f * x);
  return (e - 1.f) / (e + 1.f);
}

// ---------------------------------------------------------------------------
__global__ __launch_bounds__(256) void masksum_kernel(
    const float* __restrict__ mask, float* __restrict__ loglen) {
  int b = blockIdx.x, tid = threadIdx.x;
  int lane = tid & 63, wid = tid >> 6;
  float c = 0.f;
#pragma unroll
  for (int j = 0; j < 8; j++)
    c += (mask[(size_t)b * LL + j * 256 + tid] == 0.f) ? 1.f : 0.f;
#pragma unroll
  for (int o = 32; o >= 1; o >>= 1) c += __shfl_xor(c, o, 64);
  __shared__ float red[4];
  if (lane == 0) red[wid] = c;
  __syncthreads();
  if (tid == 0) loglen[b] = logf(1.f + red[0] + red[1] + red[2] + red[3]);
}

// ---------------------------------------------------------------------------
// Pack Wv -> bf16, layout [ntile(2)][kt(32)][chunk(1024) of 16B], with the
// XOR chunk swizzle baked in: chunk j = n*4+c holds k-quad q = c ^ ((n>>1)&3).
__global__ __launch_bounds__(256) void wvpack_kernel(
    const float* __restrict__ Wv, __hip_bfloat16* __restrict__ wvpk) {
  int t = blockIdx.x * 256 + threadIdx.x;  // 16384 threads
  int u4 = t & 127;                        // u-group of 4
  int kg = t >> 7;                         // k-group of 8 (0..127)
  int k0 = kg * 8;
  int kt = kg >> 2;
  int q = kg & 3;
  float4 f[8];
#pragma unroll
  for (int j = 0; j < 8; j++)
    f[j] = *(const float4*)(Wv + (size_t)(k0 + j) * NU + u4 * 4);
#pragma unroll
  for (int e = 0; e < 4; e++) {
    int u = u4 * 4 + e;
    int nt = u >> 8, n = u & 255;
    int c = q ^ ((n >> 1) & 3);
    int idx = nt * 32768 + kt * 1024 + n * 4 + c;
    const float* fe = (const float*)&f[0] + e;  // stride 4 floats per row
    union {
      __hip_bfloat162 h2[4];
      int4 v;
    } pk;
#pragma unroll
    for (int m = 0; m < 4; m++)
      pk.h2[m] = __float22bfloat162_rn(make_float2(fe[(2 * m) * 4], fe[(2 * m + 1) * 4]));
    ((int4*)wvpk)[idx] = pk.v;
  }
}

// ---------------------------------------------------------------------------
// h[b,u] = q@Wh + biases + log(1+ts)*Wp0 + loglen*Wp2.
__global__ __launch_bounds__(256) void h_kernel(
    const float* __restrict__ q, const float* __restrict__ Wh,
    const float* __restrict__ bh, const float* __restrict__ bv,
    const float* __restrict__ bp, const float* __restrict__ bm,
    const float* __restrict__ Wp, const int* __restrict__ ts,
    const float* __restrict__ loglen, float* __restrict__ h) {
  int u0 = blockIdx.x * 64;
  int bq = blockIdx.y;
  int tid = threadIdx.x;
  int u = tid & 63, bsub = tid >> 6;
  int b0 = bq * 8 + bsub * 2, b1 = b0 + 1;

  __shared__ float qsL[8][1024];  // 32 KB: q rows for this bq's 8 b's
#pragma unroll
  for (int j = 0; j < 8; j++) {
    int f = j * 256 + tid;  // float4 index in [0,2048)
    int bl = f >> 8, k4 = f & 255;
    *(float4*)&qsL[bl][k4 * 4] =
        *(const float4*)(q + (size_t)(bq * 8 + bl) * 1024 + k4 * 4);
  }
  __syncthreads();

  float a0e = 0.f, a0o = 0.f, a1e = 0.f, a1o = 0.f;
#pragma unroll 16
  for (int k = 0; k < 1024; k += 2) {
    float w0 = Wh[(size_t)k * NU + u0 + u];
    float w1 = Wh[(size_t)(k + 1) * NU + u0 + u];
    a0e += w0 * qsL[bsub * 2][k];
    a1e += w0 * qsL[bsub * 2 + 1][k];
    a0o += w1 * qsL[bsub * 2][k + 1];
    a1o += w1 * qsL[bsub * 2 + 1][k + 1];
  }
  float acc0 = a0e + a0o, acc1 = a1e + a1o;

  int uu = u0 + u;
  float lt = logf(1.0f + (float)ts[0]);
  float bias = bh[uu] + bv[uu] + bp[uu] + bm[uu] + lt * Wp[uu];
  float wp2 = Wp[2 * NU + uu];
  h[b0 * NU + uu] = acc0 + bias + loglen[b0] * wp2;
  h[b1 * NU + uu] = acc1 + bias + loglen[b1] * wp2;
}

// ---------------------------------------------------------------------------
// Score: S = values@Wv (bf16 MFMA), epilogue tanh(S+E)*vw reduced over u.
// 512 thr = 8 waves (2 row x 4 col), wave tile 64x64, acc[4][4] -> 64 VGPR.
// LDS ~58KB -> 2 blocks/CU x 8 waves = 16 waves/CU (4/SIMD), 2x the 256-thr
// version's latency hiding. Schedule: double-buffered LDS, ONE barrier/step,
// all VMEM issued before the MFMA phase.
__global__ __launch_bounds__(512, 4) void score_kernel(
    const float* __restrict__ values, const __hip_bfloat16* __restrict__ wvpk,
    const float* __restrict__ h, const float* __restrict__ Wp,
    const float* __restrict__ Wm, const float* __restrict__ vw,
    const float* __restrict__ prev, float* __restrict__ partial) {
  int lin = blockIdx.x;
  int group = lin >> 4, sub = lin & 15;
  int ntile = sub >> 3;                 // 0..1
  int mtile = group * 8 + (sub & 7);    // 0..511
  int tid = threadIdx.x;
  int lane = tid & 63, wid = tid >> 6;  // wid 0..7
  int wr = wid >> 2, wc = wid & 3;      // 2 x 4 wave grid
  int col = lane & 15, quad = lane >> 4;
  int b = mtile >> 4;
  int l0 = (mtile & 15) << 7;
  int rowbase = mtile << 7;

  __shared__ __align__(16) char AsB[2][8192];   // 128 rows x 64B, swizzled
  __shared__ __align__(16) char BsB[2][16384];  // 256 cols x 64B, swizzled
  __shared__ float hL[256], wp1L[256], vwL[256], wmL[5][256];
  __shared__ float loglS[128], prevs[132], scoreAcc[128];

  if (tid < 256) {
    int u = ntile * 256 + tid;
    hL[tid] = h[b * NU + u];
    wp1L[tid] = Wp[NU + u];
    vwL[tid] = vw[u];
#pragma unroll
    for (int j = 0; j < 5; j++) wmL[j][tid] = Wm[j * NU + u];
  }
  if (tid < 128) {
    loglS[tid] = __logf(2.0f + (float)(l0 + tid));
    scoreAcc[tid] = 0.f;
  }
  if (tid < 132) {
    int li = l0 - 2 + tid;
    prevs[tid] = (li >= 0 && li < LL) ? prev[(size_t)b * LL + li] : 0.f;
  }

  f32x4 acc[4][4];
  f32x4 zero4 = {0.f, 0.f, 0.f, 0.f};
#pragma unroll
  for (int i = 0; i < 4; i++)
#pragma unroll
    for (int j = 0; j < 4; j++) acc[i][j] = zero4;

  // A staging: 512 thr, 4 thr/row; thread covers 8 k (one 16B bf16 chunk).
  int row = tid >> 2, h0 = tid & 3;
  const float* abase = values + (size_t)(rowbase + row) * DV + h0 * 8;
  int s_sw = (row >> 1) & 3;
  int aoff = row * 64 + ((h0 ^ s_sw) * 16);
  const char* bbase = (const char*)wvpk + (size_t)ntile * 32 * 16384;
  int boff = tid * 16;  // 0..8191; B per kt = 16KB -> 2 GLL16/thread

  float4 preA[2][2];  // 2-deep A prefetch, 8 floats per kt

#define CVT_STORE(SLOT, DSTBUF)                                                \
  {                                                                            \
    float4 f0 = preA[SLOT][0], f1 = preA[SLOT][1];                             \
    union {                                                                    \
      __hip_bfloat162 h2[4];                                                   \
      int4 v;                                                                  \
    } pk;                                                                      \
    pk.h2[0] = __float22bfloat162_rn(make_float2(f0.x, f0.y));                 \
    pk.h2[1] = __float22bfloat162_rn(make_float2(f0.z, f0.w));                 \
    pk.h2[2] = __float22bfloat162_rn(make_float2(f1.x, f1.y));                 \
    pk.h2[3] = __float22bfloat162_rn(make_float2(f1.z, f1.w));                 \
    *(int4*)(AsB[DSTBUF] + aoff) = pk.v;                                       \
  }

  // Prologue: preA <- tiles 0,1; stage B(0)+A(0) into buf 0; preA[0] <- tile 2.
  {
#pragma unroll
    for (int d = 0; d < 2; d++) {
      preA[d][0] = *(const float4*)(abase + d * 32);
      preA[d][1] = *(const float4*)(abase + d * 32 + 4);
    }
    GLL16(bbase + boff, BsB[0] + boff);
    GLL16(bbase + boff + 8192, BsB[0] + boff + 8192);
    CVT_STORE(0, 0);
    preA[0][0] = *(const float4*)(abase + 2 * 32);
    preA[0][1] = *(const float4*)(abase + 2 * 32 + 4);
    __syncthreads();
  }

// Invariant entering KT (compute buf CBUF=KT&1):
//   slot[(KT+1)&1] holds A tile KT+1; slot[KT&1] holds A tile KT+2.
#define KSTEP(KT, CBUF, OSLOT, DO_STAGE, DO_RELOAD)                            \
  {                                                                            \
    if (DO_STAGE) {                                                            \
      const char* bsrc = bbase + (size_t)((KT) + 1) * 16384;                   \
      GLL16(bsrc + boff, BsB[(CBUF) ^ 1] + boff);                              \
      GLL16(bsrc + boff + 8192, BsB[(CBUF) ^ 1] + boff + 8192);                \
      CVT_STORE(OSLOT, (CBUF) ^ 1);                                            \
      if (DO_RELOAD) {                                                         \
        preA[OSLOT][0] = *(const float4*)(abase + ((KT) + 3) * 32);            \
        preA[OSLOT][1] = *(const float4*)(abase + ((KT) + 3) * 32 + 4);        \
      }                                                                        \
    }                                                                          \
    short8 aF[4];                                                              \
    _Pragma("unroll") for (int t = 0; t < 4; t++) {                            \
      int m = wr * 64 + t * 16 + col;                                          \
      aF[t] = *(const short8*)(AsB[CBUF] + m * 64 +                            \
                               ((quad ^ ((m >> 1) & 3)) * 16));                \
    }                                                                          \
    _Pragma("unroll") for (int tc = 0; tc < 4; tc++) {                         \
      int n = wc * 64 + tc * 16 + col;                                         \
      short8 bF =                                                              \
          *(const short8*)(BsB[CBUF] + n * 64 + ((quad ^ ((n >> 1) & 3)) * 16)); \
      _Pragma("unroll") for (int tr = 0; tr < 4; tr++) acc[tr][tc] =           \
          __builtin_amdgcn_mfma_f32_16x16x32_bf16(aF[tr], bF, acc[tr][tc], 0,  \
                                                  0, 0);                       \
    }                                                                          \
    __syncthreads();                                                           \
  }

  for (int kto = 0; kto < 14; kto++) {
    KSTEP(2 * kto, 0, 1, 1, 1);
    KSTEP(2 * kto + 1, 1, 0, 1, 1);
  }
  KSTEP(28, 0, 1, 1, 1);
  KSTEP(29, 1, 0, 1, 0);
  KSTEP(30, 0, 1, 1, 0);
  KSTEP(31, 1, 0, 0, 0);
#undef KSTEP
#undef CVT_STORE

  // Epilogue
  int rb = wr * 64;
#pragma unroll
  for (int tr = 0; tr < 4; tr++) {
    float ps[4] = {0.f, 0.f, 0.f, 0.f};
#pragma unroll
    for (int tc = 0; tc < 4; tc++) {
      int uc = wc * 64 + tc * 16 + col;
      float hh = hL[uc], wp1 = wp1L[uc], vv = vwL[uc];
      float m0 = wmL[0][uc], m1 = wmL[1][uc], m2 = wmL[2][uc],
            m3 = wmL[3][uc], m4 = wmL[4][uc];
      int r0 = rb + tr * 16 + quad * 4;
#pragma unroll
      for (int i = 0; i < 4; i++) {
        int r = r0 + i;
        float e = hh + loglS[r] * wp1 + prevs[r] * m0 + prevs[r + 1] * m1 +
                  prevs[r + 2] * m2 + prevs[r + 3] * m3 + prevs[r + 4] * m4;
        float sv = acc[tr][tc][i] + e;
        ps[i] += fast_tanh(sv) * vv;
      }
    }
#pragma unroll
    for (int i = 0; i < 4; i++) {
      float v = ps[i];
      v += __shfl_xor(v, 1, 64);
      v += __shfl_xor(v, 2, 64);
      v += __shfl_xor(v, 4, 64);
      v += __shfl_xor(v, 8, 64);
      if (col == 0) atomicAdd(&scoreAcc[rb + tr * 16 + quad * 4 + i], v);
    }
  }
  __syncthreads();
  if (tid < 128)
    partial[(size_t)ntile * NM + rowbase + tid] = scoreAcc[tid];
}

// ---------------------------------------------------------------------------
__global__ __launch_bounds__(256) void softmax_kernel(
    const float* __restrict__ partial, const float* __restrict__ mask,
    float* __restrict__ aw) {
  int b = blockIdx.x, tid = threadIdx.x;
  int lane = tid & 63, wid = tid >> 6;
  __shared__ float redmax[4], redsum[4];
  float sc[8];
  float mx = -3.0e38f;
#pragma unroll
  for (int j = 0; j < 8; j++) {
    size_t base = (size_t)b * LL + j * 256 + tid;
    float s = partial[base] + partial[(size_t)NM + base];
    s += mask[base] * -1.0e9f;
    sc[j] = s;
    mx = fmaxf(mx, s);
  }
#pragma unroll
  for (int o = 32; o >= 1; o >>= 1) mx = fmaxf(mx, __shfl_xor(mx, o, 64));
  if (lane == 0) redmax[wid] = mx;
  __syncthreads();
  mx = fmaxf(fmaxf(redmax[0], redmax[1]), fmaxf(redmax[2], redmax[3]));
  float sum = 0.f;
#pragma unroll
  for (int j = 0; j < 8; j++) {
    float e = __expf(sc[j] - mx);
    sc[j] = e;
    sum += e;
  }
#pragma unroll
  for (int o = 32; o >= 1; o >>= 1) sum += __shfl_xor(sum, o, 64);
  if (lane == 0) redsum[wid] = sum;
  __syncthreads();
  sum = redsum[0] + redsum[1] + redsum[2] + redsum[3];
  float inv = 1.0f / sum;
#pragma unroll
  for (int j = 0; j < 8; j++)
    aw[(size_t)b * LL + j * 256 + tid] = sc[j] * inv;
}

// ---------------------------------------------------------------------------
// ctx: 256 blocks (32 b x 8 chunks of 256 rows) x 1024 thr -> full-chip BW.
// Thread (rg, s): rows rg*64..+63 of the chunk, d-slot s (float4). LDS
// reduce over rg, then one atomicAdd x4 per (b,s) per block (8-way contention).
__global__ __launch_bounds__(1024) void ctx_kernel(
    const float* __restrict__ values, const float* __restrict__ aw,
    float* __restrict__ out) {
  int b = blockIdx.x >> 3, chunk = blockIdx.x & 7;
  int tid = threadIdx.x;
  int s = tid & 255, rg = tid >> 8;
  int l0 = chunk * 256;

  __shared__ float awL[256];
  __shared__ f32x4 red[4][256];

  if (tid < 256) awL[tid] = aw[(size_t)b * LL + l0 + tid];
  __syncthreads();

  const float4* vbase =
      (const float4*)(values + ((size_t)b * LL + l0 + rg * 64) * DV) + s;
  const float* awr = awL + rg * 64;
  float4 acc = make_float4(0.f, 0.f, 0.f, 0.f);
  for (int i0 = 0; i0 < 64; i0 += 8) {
    float4 v[8];
#pragma unroll
    for (int j = 0; j < 8; j++) v[j] = vbase[(size_t)(i0 + j) * 256];
#pragma unroll
    for (int j = 0; j < 8; j++) {
      float w = awr[i0 + j];
      acc.x += w * v[j].x;
      acc.y += w * v[j].y;
      acc.z += w * v[j].z;
      acc.w += w * v[j].w;
    }
  }
  f32x4 a4 = {acc.x, acc.y, acc.z, acc.w};
  red[rg][s] = a4;
  __syncthreads();
  if (tid < 256) {
    f32x4 r = red[0][s];
    f32x4 r1 = red[1][s], r2 = red[2][s], r3 = red[3][s];
    r += r1;
    r += r2;
    r += r3;
    float* o = out + (size_t)b * DV + s * 4;
    atomicAdd(o + 0, r[0]);
    atomicAdd(o + 1, r[1]);
    atomicAdd(o + 2, r[2]);
    atomicAdd(o + 3, r[3]);
  }
}

// ---------------------------------------------------------------------------
extern "C" void kernel_launch(void* const* d_in, const int* in_sizes, int n_in,
                              void* d_out, int out_size, void* d_ws,
                              size_t ws_size, hipStream_t stream) {
  const float* query = (const float*)d_in[0];
  const float* values = (const float*)d_in[1];
  const float* mask = (const float*)d_in[2];
  const float* prev = (const float*)d_in[3];
  const int* ts = (const int*)d_in[4];
  const float* Wh = (const float*)d_in[5];
  const float* bh = (const float*)d_in[6];
  const float* Wv = (const float*)d_in[7];
  const float* bv = (const float*)d_in[8];
  const float* Wp = (const float*)d_in[9];
  const float* bp = (const float*)d_in[10];
  const float* Wm = (const float*)d_in[11];
  const float* bm = (const float*)d_in[12];
  const float* vw = (const float*)d_in[13];
  // d_in[14] = vb: cancels under softmax.

  float* out = (float*)d_out;   // [0,32768) ctx, [32768,98304) aw
  float* ws = (float*)d_ws;
  float* loglen = ws;                    // 32 f
  float* h = ws + 1024;                  // 16384 f
  float* partial = ws + 32768;           // 2*65536 f
  __hip_bfloat16* wvpk =
      (__hip_bfloat16*)((char*)d_ws + (size_t)163840 * 4);  // 1 MB
  float* aw = out + 32768;

  hipMemsetAsync(d_out, 0, 32768 * sizeof(float), stream);  // ctx accumulator
  masksum_kernel<<<NB, 256, 0, stream>>>(mask, loglen);
  wvpack_kernel<<<64, 256, 0, stream>>>(Wv, wvpk);
  h_kernel<<<dim3(8, 4), 256, 0, stream>>>(query, Wh, bh, bv, bp, bm, Wp, ts,
                                           loglen, h);
  score_kernel<<<1024, 512, 0, stream>>>(values, wvpk, h, Wp, Wm, vw, prev,
                                         partial);
  softmax_kernel<<<NB, 256, 0, stream>>>(partial, mask, aw);
  ctx_kernel<<<256, 1024, 0, stream>>>(values, aw, out);
}

// Round 6
// 515.298 us; speedup vs baseline: 1.0543x; 1.0171x over previous
//
#include <hip/hip_runtime.h>
#include <hip/hip_bf16.h>
#include <math.h>

// B=32, L=2048, D_Q=D_V=1024, UNITS=512
#define NB 32
#define LL 2048
#define DV 1024
#define NU 512
#define NM (NB * LL)

typedef __attribute__((ext_vector_type(8))) short short8;
typedef __attribute__((ext_vector_type(4))) float f32x4;

#define GLL16(g, l)                                                            \
  __builtin_amdgcn_global_load_lds(                                            \
      (const __attribute__((address_space(1))) void*)(g),                      \
      (__attribute__((address_space(3))) void*)(l), 16, 0, 0)

__device__ __forceinline__ float fast_tanh(float x) {
  x = fminf(fmaxf(x, -15.f), 15.f);
  float e = __expf(2.f * x);
  return (e - 1.f) / (e + 1.f);
}

// ---------------------------------------------------------------------------
// prep: blocks 0..63 pack Wv -> bf16 (swizzled layout); blocks 64..95 compute
// h[b,u] = q@Wh + biases + log(1+ts)*Wp0 + log(1+masksum)*Wp2, with the
// mask-length reduction inlined.
__global__ __launch_bounds__(256) void prep_kernel(
    const float* __restrict__ Wv, __hip_bfloat16* __restrict__ wvpk,
    const float* __restrict__ q, const float* __restrict__ Wh,
    const float* __restrict__ bh, const float* __restrict__ bv,
    const float* __restrict__ bp, const float* __restrict__ bm,
    const float* __restrict__ Wp, const int* __restrict__ ts,
    const float* __restrict__ mask, float* __restrict__ h) {
  if (blockIdx.x < 64) {
    // ---- wvpack: register transpose, coalesced reads.
    int t = blockIdx.x * 256 + threadIdx.x;  // 16384 threads
    int u4 = t & 127;
    int kg = t >> 7;
    int k0 = kg * 8;
    int kt = kg >> 2;
    int qd = kg & 3;
    float4 f[8];
#pragma unroll
    for (int j = 0; j < 8; j++)
      f[j] = *(const float4*)(Wv + (size_t)(k0 + j) * NU + u4 * 4);
#pragma unroll
    for (int e = 0; e < 4; e++) {
      int u = u4 * 4 + e;
      int nt = u >> 8, n = u & 255;
      int c = qd ^ ((n >> 1) & 3);
      int idx = nt * 32768 + kt * 1024 + n * 4 + c;
      const float* fe = (const float*)&f[0] + e;
      union {
        __hip_bfloat162 h2[4];
        int4 v;
      } pk;
#pragma unroll
      for (int m = 0; m < 4; m++)
        pk.h2[m] =
            __float22bfloat162_rn(make_float2(fe[(2 * m) * 4], fe[(2 * m + 1) * 4]));
      ((int4*)wvpk)[idx] = pk.v;
    }
    return;
  }
  // ---- h part
  int idx2 = blockIdx.x - 64;
  int u0 = (idx2 & 7) * 64;
  int bq = idx2 >> 3;
  int tid = threadIdx.x;

  __shared__ float qsL[8][1024];  // 32 KB
  __shared__ float cnt[8], lgl[8];

  // inline masksum for this bq's 8 b's: 32 threads per b.
  {
    int g = tid & 31, bl = tid >> 5;
    const float4* mrow =
        (const float4*)(mask + (size_t)(bq * 8 + bl) * LL) + g * 16;
    float c = 0.f;
#pragma unroll
    for (int j = 0; j < 16; j++) {
      float4 m = mrow[j];
      c += (m.x == 0.f ? 1.f : 0.f) + (m.y == 0.f ? 1.f : 0.f) +
           (m.z == 0.f ? 1.f : 0.f) + (m.w == 0.f ? 1.f : 0.f);
    }
#pragma unroll
    for (int o = 16; o >= 1; o >>= 1) c += __shfl_xor(c, o, 64);
    if (g == 0) cnt[bl] = c;
  }
  __syncthreads();
  if (tid < 8) lgl[tid] = logf(1.f + cnt[tid]);

  // stage q rows
#pragma unroll
  for (int j = 0; j < 8; j++) {
    int f = j * 256 + tid;
    int bl = f >> 8, k4 = f & 255;
    *(float4*)&qsL[bl][k4 * 4] =
        *(const float4*)(q + (size_t)(bq * 8 + bl) * 1024 + k4 * 4);
  }
  __syncthreads();

  int u = tid & 63, bsub = tid >> 6;
  int b0 = bq * 8 + bsub * 2, b1 = b0 + 1;
  float a0e = 0.f, a0o = 0.f, a1e = 0.f, a1o = 0.f;
#pragma unroll 16
  for (int k = 0; k < 1024; k += 2) {
    float w0 = Wh[(size_t)k * NU + u0 + u];
    float w1 = Wh[(size_t)(k + 1) * NU + u0 + u];
    a0e += w0 * qsL[bsub * 2][k];
    a1e += w0 * qsL[bsub * 2 + 1][k];
    a0o += w1 * qsL[bsub * 2][k + 1];
    a1o += w1 * qsL[bsub * 2 + 1][k + 1];
  }
  float acc0 = a0e + a0o, acc1 = a1e + a1o;

  int uu = u0 + u;
  float lt = logf(1.0f + (float)ts[0]);
  float bias = bh[uu] + bv[uu] + bp[uu] + bm[uu] + lt * Wp[uu];
  float wp2 = Wp[2 * NU + uu];
  h[b0 * NU + uu] = acc0 + bias + lgl[bsub * 2] * wp2;
  h[b1 * NU + uu] = acc1 + bias + lgl[bsub * 2 + 1] * wp2;
}

// ---------------------------------------------------------------------------
// Score: S = values@Wv (bf16 MFMA), epilogue tanh(S+E)*vw reduced over u.
// EXACT R4 schedule (verified passing): 512 thr = 8 waves (2x4), wave tile
// 64x64, acc[4][4]; double-buffered LDS, __syncthreads-based, one barrier
// per K-step. (The R5 raw-barrier counted-vmcnt variant raced — reverted.)
__global__ __launch_bounds__(512, 4) void score_kernel(
    const float* __restrict__ values, const __hip_bfloat16* __restrict__ wvpk,
    const float* __restrict__ h, const float* __restrict__ Wp,
    const float* __restrict__ Wm, const float* __restrict__ vw,
    const float* __restrict__ prev, float* __restrict__ partial) {
  int lin = blockIdx.x;
  int group = lin >> 4, sub = lin & 15;
  int ntile = sub >> 3;                 // 0..1
  int mtile = group * 8 + (sub & 7);    // 0..511
  int tid = threadIdx.x;
  int lane = tid & 63, wid = tid >> 6;  // wid 0..7
  int wr = wid >> 2, wc = wid & 3;      // 2 x 4 wave grid
  int col = lane & 15, quad = lane >> 4;
  int b = mtile >> 4;
  int l0 = (mtile & 15) << 7;
  int rowbase = mtile << 7;

  __shared__ __align__(16) char AsB[2][8192];   // 128 rows x 64B, swizzled
  __shared__ __align__(16) char BsB[2][16384];  // 256 cols x 64B, swizzled
  __shared__ float hL[256], wp1L[256], vwL[256], wmL[5][256];
  __shared__ float loglS[128], prevs[132], scoreAcc[128];

  if (tid < 256) {
    int u = ntile * 256 + tid;
    hL[tid] = h[b * NU + u];
    wp1L[tid] = Wp[NU + u];
    vwL[tid] = vw[u];
#pragma unroll
    for (int j = 0; j < 5; j++) wmL[j][tid] = Wm[j * NU + u];
  }
  if (tid < 128) {
    loglS[tid] = __logf(2.0f + (float)(l0 + tid));
    scoreAcc[tid] = 0.f;
  }
  if (tid < 132) {
    int li = l0 - 2 + tid;
    prevs[tid] = (li >= 0 && li < LL) ? prev[(size_t)b * LL + li] : 0.f;
  }

  f32x4 acc[4][4];
  f32x4 zero4 = {0.f, 0.f, 0.f, 0.f};
#pragma unroll
  for (int i = 0; i < 4; i++)
#pragma unroll
    for (int j = 0; j < 4; j++) acc[i][j] = zero4;

  // A staging: 512 thr, 4 thr/row; thread covers 8 k (one 16B bf16 chunk).
  int row = tid >> 2, h0 = tid & 3;
  const float* abase = values + (size_t)(rowbase + row) * DV + h0 * 8;
  int s_sw = (row >> 1) & 3;
  int aoff = row * 64 + ((h0 ^ s_sw) * 16);
  const char* bbase = (const char*)wvpk + (size_t)ntile * 32 * 16384;
  int boff = tid * 16;  // B per kt = 16KB -> 2 GLL16/thread

  float4 preA[2][2];  // 2-deep A prefetch, 8 floats per kt

#define CVT_STORE(SLOT, DSTBUF)                                                \
  {                                                                            \
    float4 f0 = preA[SLOT][0], f1 = preA[SLOT][1];                             \
    union {                                                                    \
      __hip_bfloat162 h2[4];                                                   \
      int4 v;                                                                  \
    } pk;                                                                      \
    pk.h2[0] = __float22bfloat162_rn(make_float2(f0.x, f0.y));                 \
    pk.h2[1] = __float22bfloat162_rn(make_float2(f0.z, f0.w));                 \
    pk.h2[2] = __float22bfloat162_rn(make_float2(f1.x, f1.y));                 \
    pk.h2[3] = __float22bfloat162_rn(make_float2(f1.z, f1.w));                 \
    *(int4*)(AsB[DSTBUF] + aoff) = pk.v;                                       \
  }

  // Prologue: preA <- tiles 0,1; stage B(0)+A(0) into buf 0; preA[0] <- tile 2.
  {
#pragma unroll
    for (int d = 0; d < 2; d++) {
      preA[d][0] = *(const float4*)(abase + d * 32);
      preA[d][1] = *(const float4*)(abase + d * 32 + 4);
    }
    GLL16(bbase + boff, BsB[0] + boff);
    GLL16(bbase + boff + 8192, BsB[0] + boff + 8192);
    CVT_STORE(0, 0);
    preA[0][0] = *(const float4*)(abase + 2 * 32);
    preA[0][1] = *(const float4*)(abase + 2 * 32 + 4);
    __syncthreads();
  }

// Invariant entering KT (compute buf CBUF=KT&1):
//   slot[(KT+1)&1] holds A tile KT+1; slot[KT&1] holds A tile KT+2.
#define KSTEP(KT, CBUF, OSLOT, DO_STAGE, DO_RELOAD)                            \
  {                                                                            \
    if (DO_STAGE) {                                                            \
      const char* bsrc = bbase + (size_t)((KT) + 1) * 16384;                   \
      GLL16(bsrc + boff, BsB[(CBUF) ^ 1] + boff);                              \
      GLL16(bsrc + boff + 8192, BsB[(CBUF) ^ 1] + boff + 8192);                \
      CVT_STORE(OSLOT, (CBUF) ^ 1);                                            \
      if (DO_RELOAD) {                                                         \
        preA[OSLOT][0] = *(const float4*)(abase + ((KT) + 3) * 32);            \
        preA[OSLOT][1] = *(const float4*)(abase + ((KT) + 3) * 32 + 4);        \
      }                                                                        \
    }                                                                          \
    short8 aF[4];                                                              \
    _Pragma("unroll") for (int t = 0; t < 4; t++) {                            \
      int m = wr * 64 + t * 16 + col;                                          \
      aF[t] = *(const short8*)(AsB[CBUF] + m * 64 +                            \
                               ((quad ^ ((m >> 1) & 3)) * 16));                \
    }                                                                          \
    _Pragma("unroll") for (int tc = 0; tc < 4; tc++) {                         \
      int n = wc * 64 + tc * 16 + col;                                         \
      short8 bF =                                                              \
          *(const short8*)(BsB[CBUF] + n * 64 + ((quad ^ ((n >> 1) & 3)) * 16)); \
      _Pragma("unroll") for (int tr = 0; tr < 4; tr++) acc[tr][tc] =           \
          __builtin_amdgcn_mfma_f32_16x16x32_bf16(aF[tr], bF, acc[tr][tc], 0,  \
                                                  0, 0);                       \
    }                                                                          \
    __syncthreads();                                                           \
  }

  for (int kto = 0; kto < 14; kto++) {
    KSTEP(2 * kto, 0, 1, 1, 1);
    KSTEP(2 * kto + 1, 1, 0, 1, 1);
  }
  KSTEP(28, 0, 1, 1, 1);
  KSTEP(29, 1, 0, 1, 0);
  KSTEP(30, 0, 1, 1, 0);
  KSTEP(31, 1, 0, 0, 0);
#undef KSTEP
#undef CVT_STORE

  // Epilogue
  int rb = wr * 64;
#pragma unroll
  for (int tr = 0; tr < 4; tr++) {
    float ps[4] = {0.f, 0.f, 0.f, 0.f};
#pragma unroll
    for (int tc = 0; tc < 4; tc++) {
      int uc = wc * 64 + tc * 16 + col;
      float hh = hL[uc], wp1 = wp1L[uc], vv = vwL[uc];
      float m0 = wmL[0][uc], m1 = wmL[1][uc], m2 = wmL[2][uc],
            m3 = wmL[3][uc], m4 = wmL[4][uc];
      int r0 = rb + tr * 16 + quad * 4;
#pragma unroll
      for (int i = 0; i < 4; i++) {
        int r = r0 + i;
        float e = hh + loglS[r] * wp1 + prevs[r] * m0 + prevs[r + 1] * m1 +
                  prevs[r + 2] * m2 + prevs[r + 3] * m3 + prevs[r + 4] * m4;
        float sv = acc[tr][tc][i] + e;
        ps[i] += fast_tanh(sv) * vv;
      }
    }
#pragma unroll
    for (int i = 0; i < 4; i++) {
      float v = ps[i];
      v += __shfl_xor(v, 1, 64);
      v += __shfl_xor(v, 2, 64);
      v += __shfl_xor(v, 4, 64);
      v += __shfl_xor(v, 8, 64);
      if (col == 0) atomicAdd(&scoreAcc[rb + tr * 16 + quad * 4 + i], v);
    }
  }
  __syncthreads();
  if (tid < 128)
    partial[(size_t)ntile * NM + rowbase + tid] = scoreAcc[tid];
}

// ---------------------------------------------------------------------------
// post: fused softmax + ctx. Grid 256 = (b, chunk of 256 rows) x 1024 thr.
// Each block recomputes the cheap softmax stats for its b, writes its aw
// chunk, then accumulates its ctx chunk with an in-block LDS reduction and
// one atomicAdd set per (b, d-slot).
__global__ __launch_bounds__(1024) void post_kernel(
    const float* __restrict__ partial, const float* __restrict__ mask,
    const float* __restrict__ values, float* __restrict__ aw,
    float* __restrict__ out) {
  int b = blockIdx.x >> 3, chunk = blockIdx.x & 7;
  int tid = threadIdx.x;
  int lane = tid & 63, wid = tid >> 6;  // 16 waves
  __shared__ float wmx[16], wsm[16];
  __shared__ float awL[256];
  __shared__ f32x4 red[4][256];

  size_t base = (size_t)b * LL;
  float s1, s2;
  {
    size_t l1 = base + tid, l2 = base + tid + 1024;
    s1 = partial[l1] + partial[(size_t)NM + l1] + mask[l1] * -1.0e9f;
    s2 = partial[l2] + partial[(size_t)NM + l2] + mask[l2] * -1.0e9f;
  }
  float mx = fmaxf(s1, s2);
#pragma unroll
  for (int o = 32; o >= 1; o >>= 1) mx = fmaxf(mx, __shfl_xor(mx, o, 64));
  if (lane == 0) wmx[wid] = mx;
  __syncthreads();
  mx = wmx[0];
#pragma unroll
  for (int j = 1; j < 16; j++) mx = fmaxf(mx, wmx[j]);
  float e = __expf(s1 - mx) + __expf(s2 - mx);
#pragma unroll
  for (int o = 32; o >= 1; o >>= 1) e += __shfl_xor(e, o, 64);
  if (lane == 0) wsm[wid] = e;
  __syncthreads();
  float sum = 0.f;
#pragma unroll
  for (int j = 0; j < 16; j++) sum += wsm[j];
  float inv = 1.0f / sum;

  int l0 = chunk * 256;
  if (tid < 256) {
    size_t l = base + l0 + tid;
    float s = partial[l] + partial[(size_t)NM + l] + mask[l] * -1.0e9f;
    float a = __expf(s - mx) * inv;
    aw[l] = a;
    awL[tid] = a;
  }
  __syncthreads();

  int s = tid & 255, rg = tid >> 8;
  const float4* vbase =
      (const float4*)(values + ((size_t)b * LL + l0 + rg * 64) * DV) + s;
  const float* awr = awL + rg * 64;
  float4 acc = make_float4(0.f, 0.f, 0.f, 0.f);
  for (int i0 = 0; i0 < 64; i0 += 8) {
    float4 v[8];
#pragma unroll
    for (int j = 0; j < 8; j++) v[j] = vbase[(size_t)(i0 + j) * 256];
#pragma unroll
    for (int j = 0; j < 8; j++) {
      float w = awr[i0 + j];
      acc.x += w * v[j].x;
      acc.y += w * v[j].y;
      acc.z += w * v[j].z;
      acc.w += w * v[j].w;
    }
  }
  f32x4 a4 = {acc.x, acc.y, acc.z, acc.w};
  red[rg][s] = a4;
  __syncthreads();
  if (tid < 256) {
    f32x4 r = red[0][s];
    f32x4 r1 = red[1][s], r2 = red[2][s], r3 = red[3][s];
    r += r1;
    r += r2;
    r += r3;
    float* o = out + (size_t)b * DV + s * 4;
    atomicAdd(o + 0, r[0]);
    atomicAdd(o + 1, r[1]);
    atomicAdd(o + 2, r[2]);
    atomicAdd(o + 3, r[3]);
  }
}

// ---------------------------------------------------------------------------
extern "C" void kernel_launch(void* const* d_in, const int* in_sizes, int n_in,
                              void* d_out, int out_size, void* d_ws,
                              size_t ws_size, hipStream_t stream) {
  const float* query = (const float*)d_in[0];
  const float* values = (const float*)d_in[1];
  const float* mask = (const float*)d_in[2];
  const float* prev = (const float*)d_in[3];
  const int* ts = (const int*)d_in[4];
  const float* Wh = (const float*)d_in[5];
  const float* bh = (const float*)d_in[6];
  const float* Wv = (const float*)d_in[7];
  const float* bv = (const float*)d_in[8];
  const float* Wp = (const float*)d_in[9];
  const float* bp = (const float*)d_in[10];
  const float* Wm = (const float*)d_in[11];
  const float* bm = (const float*)d_in[12];
  const float* vw = (const float*)d_in[13];
  // d_in[14] = vb: cancels under softmax.

  float* out = (float*)d_out;   // [0,32768) ctx, [32768,98304) aw
  float* ws = (float*)d_ws;
  float* h = ws + 1024;                  // 16384 f
  float* partial = ws + 32768;           // 2*65536 f
  __hip_bfloat16* wvpk =
      (__hip_bfloat16*)((char*)d_ws + (size_t)163840 * 4);  // 1 MB
  float* aw = out + 32768;

  hipMemsetAsync(d_out, 0, 32768 * sizeof(float), stream);  // ctx accumulator
  prep_kernel<<<96, 256, 0, stream>>>(Wv, wvpk, query, Wh, bh, bv, bp, bm, Wp,
                                      ts, mask, h);
  score_kernel<<<1024, 512, 0, stream>>>(values, wvpk, h, Wp, Wm, vw, prev,
                                         partial);
  post_kernel<<<256, 1024, 0, stream>>>(partial, mask, values, aw, out);
}